// Round 7
// baseline (8925.879 us; speedup 1.0000x reference)
//
#include <hip/hip_runtime.h>
#include <stdint.h>

#define BATCH 8192
#define NDEN  8192
#define KDIM  2048
#define TOPK  819

typedef unsigned long long u64;

// ---------------- kernel 0: boost in f64 ----------------
__global__ void boost64_kernel(const float* __restrict__ duty, double* __restrict__ boost) {
    int i = blockIdx.x * blockDim.x + threadIdx.x;
    if (i < NDEN) boost[i] = exp(2.0 * (0.1 - (double)duty[i]));
}

// ---------------- kernel 1: y = x @ (w*mask)^T + bias, full f64, hi/lo split ----------------
// BM=128, BN=64, BK=16, 256 threads, per-thread 8x4 f64 accumulator.
__global__ __launch_bounds__(256) void masked_gemm_f64(
    const float* __restrict__ x,      // [BATCH, KDIM] f32
    const float* __restrict__ w,      // [NDEN, KDIM] f32
    const int*   __restrict__ wmask,  // [NDEN, KDIM] int 0/1
    const float* __restrict__ bias,   // [NDEN] f32
    float*       __restrict__ yhi,    // [BATCH, NDEN] f32(y64)
    float*       __restrict__ ylo)    // [BATCH, NDEN] f32(y64 - hi)
{
    constexpr int BM = 128, BN = 64, BK = 16;
    __shared__ double As[BK][BM + 1];
    __shared__ double Bs[BK][BN + 1];

    const int tid = threadIdx.x;
    const int m0 = blockIdx.y * BM;
    const int n0 = blockIdx.x * BN;
    const int tx = tid & 15;    // N micro (4 cols)
    const int ty = tid >> 4;    // M micro (8 rows)
    const int lrow = tid >> 2;          // 0..63
    const int lcol = (tid & 3) << 2;    // 0,4,8,12

    double acc[8][4];
#pragma unroll
    for (int i = 0; i < 8; ++i)
#pragma unroll
        for (int j = 0; j < 4; ++j) acc[i][j] = 0.0;

    const float* xg = x + (size_t)(m0 + lrow) * KDIM + lcol;
    const float* wg = w + (size_t)(n0 + lrow) * KDIM + lcol;
    const int*   mg = wmask + (size_t)(n0 + lrow) * KDIM + lcol;

    for (int k0 = 0; k0 < KDIM; k0 += BK) {
#pragma unroll
        for (int i = 0; i < 2; ++i) {
            float4 av = *(const float4*)(xg + (size_t)(i * 64) * KDIM + k0);
            const int r = lrow + i * 64;
            As[lcol + 0][r] = (double)av.x;
            As[lcol + 1][r] = (double)av.y;
            As[lcol + 2][r] = (double)av.z;
            As[lcol + 3][r] = (double)av.w;
        }
        {
            float4 wv = *(const float4*)(wg + k0);
            int4   mv = *(const int4*)(mg + k0);
            Bs[lcol + 0][lrow] = mv.x ? (double)wv.x : 0.0;
            Bs[lcol + 1][lrow] = mv.y ? (double)wv.y : 0.0;
            Bs[lcol + 2][lrow] = mv.z ? (double)wv.z : 0.0;
            Bs[lcol + 3][lrow] = mv.w ? (double)wv.w : 0.0;
        }
        __syncthreads();
#pragma unroll
        for (int kk = 0; kk < BK; ++kk) {
            double a[8], b[4];
#pragma unroll
            for (int i = 0; i < 8; ++i) a[i] = As[kk][ty * 8 + i];
#pragma unroll
            for (int j = 0; j < 4; ++j) b[j] = Bs[kk][tx * 4 + j];
#pragma unroll
            for (int i = 0; i < 8; ++i)
#pragma unroll
                for (int j = 0; j < 4; ++j)
                    acc[i][j] = fma(a[i], b[j], acc[i][j]);
        }
        __syncthreads();
    }

    double bb[4];
#pragma unroll
    for (int j = 0; j < 4; ++j) bb[j] = (double)bias[n0 + tx * 4 + j];
#pragma unroll
    for (int r = 0; r < 8; ++r) {
        float4 oh, ol;
        float* ph = (float*)&oh;
        float* pl = (float*)&ol;
#pragma unroll
        for (int j = 0; j < 4; ++j) {
            double v = acc[r][j] + bb[j];
            float  h = (float)v;
            ph[j] = h;
            pl[j] = (float)(v - (double)h);
        }
        const size_t off = (size_t)(m0 + ty * 8 + r) * NDEN + n0 + tx * 4;
        *(float4*)(yhi + off) = oh;
        *(float4*)(ylo + off) = ol;
    }
}

// ---------------- kernel 2: exact f64-key top-k (no band machinery) ----------------
__device__ __forceinline__ u64 dkey(double f) {
    u64 u = (u64)__double_as_longlong(f);
    return (u & 0x8000000000000000ull) ? ~u : (u | 0x8000000000000000ull);
}

__global__ __launch_bounds__(256) void topk64(
    float* __restrict__ yhi, const float* __restrict__ ylo,
    const double* __restrict__ boost)
{
    const int row  = blockIdx.x;
    const int tid  = threadIdx.x;
    const int lane = tid & 63;
    float* hrow = yhi + (size_t)row * NDEN;
    const float* lrow = ylo + (size_t)row * NDEN;

    __shared__ unsigned cnt[64];
    if (tid < 64) cnt[tid] = 0u;

    // exact f64 score keys, 32 per thread
    u64 kv[32];
#pragma unroll
    for (int i = 0; i < 8; ++i) {
        float4 h = ((const float4*)hrow)[i * 256 + tid];
        float4 l = ((const float4*)lrow)[i * 256 + tid];
        const int col0 = (i * 256 + tid) * 4;
        kv[i * 4 + 0] = dkey(((double)h.x + (double)l.x) * boost[col0 + 0]);
        kv[i * 4 + 1] = dkey(((double)h.y + (double)l.y) * boost[col0 + 1]);
        kv[i * 4 + 2] = dkey(((double)h.z + (double)l.z) * boost[col0 + 2]);
        kv[i * 4 + 3] = dkey(((double)h.w + (double)l.w) * boost[col0 + 3]);
    }
    __syncthreads();

    // 64-bit radix bisect for the K-th largest key
    u64 prefix = 0ull;
    for (int b = 63; b >= 0; --b) {
        const u64 t = prefix | (1ull << b);
        int c = 0;
#pragma unroll
        for (int j = 0; j < 32; ++j) c += (kv[j] >= t) ? 1 : 0;
#pragma unroll
        for (int off = 32; off > 0; off >>= 1) c += __shfl_down(c, off);
        if (lane == 0) atomicAdd(&cnt[b], (unsigned)c);
        __syncthreads();
        if (cnt[b] >= TOPK) prefix = t;
    }

    // winners: key >= prefix (prefix == exact K-th largest f64 key)
#pragma unroll
    for (int i = 0; i < 8; ++i) {
        float4 h = ((const float4*)hrow)[i * 256 + tid];
        float4 o;
        o.x = (kv[i * 4 + 0] >= prefix) ? h.x : 0.0f;
        o.y = (kv[i * 4 + 1] >= prefix) ? h.y : 0.0f;
        o.z = (kv[i * 4 + 2] >= prefix) ? h.z : 0.0f;
        o.w = (kv[i * 4 + 3] >= prefix) ? h.w : 0.0f;
        ((float4*)hrow)[i * 256 + tid] = o;
    }
}

// ---------------- launcher ----------------
extern "C" void kernel_launch(void* const* d_in, const int* in_sizes, int n_in,
                              void* d_out, int out_size, void* d_ws, size_t ws_size,
                              hipStream_t stream) {
    const float* x     = (const float*)d_in[0];
    const float* w     = (const float*)d_in[1];
    const float* bias  = (const float*)d_in[2];
    const float* duty  = (const float*)d_in[3];
    const int*   wmask = (const int*)d_in[4];

    float*  yhi   = (float*)d_out;
    float*  ylo   = (float*)d_ws;                                    // 268435456 B
    double* boost = (double*)((char*)d_ws + (size_t)BATCH * NDEN * 4); // +65536 B

    boost64_kernel<<<NDEN / 256, 256, 0, stream>>>(duty, boost);
    dim3 grid(NDEN / 64, BATCH / 128);
    masked_gemm_f64<<<grid, 256, 0, stream>>>(x, w, wmask, bias, yhi, ylo);
    topk64<<<BATCH, 256, 0, stream>>>(yhi, ylo, boost);
}

// Round 11
// 7696.704 us; speedup vs baseline: 1.1597x; 1.1597x over previous
//
#include <hip/hip_runtime.h>
#include <stdint.h>

#define BATCH 8192
#define NDEN  8192
#define KDIM  2048
#define TOPK  819

typedef unsigned long long u64;

// ---------------- kernel 0: boost in f64 ----------------
__global__ void boost64_kernel(const float* __restrict__ duty, double* __restrict__ boost) {
    int i = blockIdx.x * blockDim.x + threadIdx.x;
    if (i < NDEN) boost[i] = exp(2.0 * (0.1 - (double)duty[i]));
}

// ---------------- kernel 1: y = x @ (w*mask)^T + bias, full f64, hi/lo split ----------------
// BM=128, BN=128, BK=16, 256 threads, 8x8 f64 micro-tile.
// Thread columns: n0 + 2*tx + 32*j + c  (j=0..3, c=0..1) -> conflict-free LDS reads
// (b128 pairs stride 16B across 16 lanes = 16 bank-pairs, 2-way alias only).
__global__ __launch_bounds__(256) void masked_gemm_f64(
    const float* __restrict__ x,      // [BATCH, KDIM] f32
    const float* __restrict__ w,      // [NDEN, KDIM] f32
    const int*   __restrict__ wmask,  // [NDEN, KDIM] int 0/1
    const float* __restrict__ bias,   // [NDEN] f32
    float*       __restrict__ yhi,    // [BATCH, NDEN] f32(y64)
    float*       __restrict__ ylo)    // [BATCH, NDEN] f32(y64 - hi)
{
    constexpr int BM = 128, BN = 128, BK = 16;
    __shared__ double As[BK][BM + 1];
    __shared__ double Bs[BK][BN + 1];

    const int tid = threadIdx.x;
    const int m0 = blockIdx.y * BM;
    const int n0 = blockIdx.x * BN;
    const int tx = tid & 15;            // N micro base (cols 2*tx + 32*j + c)
    const int ty = tid >> 4;            // M micro (rows ty*8 + i)
    const int lrow = tid >> 2;          // 0..63 staging row
    const int lcol = (tid & 3) << 2;    // 0,4,8,12 staging k-offset

    double acc[8][8];
#pragma unroll
    for (int i = 0; i < 8; ++i)
#pragma unroll
        for (int j = 0; j < 8; ++j) acc[i][j] = 0.0;

    const float* xg = x + (size_t)(m0 + lrow) * KDIM + lcol;
    const float* wg = w + (size_t)(n0 + lrow) * KDIM + lcol;
    const int*   mg = wmask + (size_t)(n0 + lrow) * KDIM + lcol;

    for (int k0 = 0; k0 < KDIM; k0 += BK) {
        // stage A: 128 rows x 16 k
#pragma unroll
        for (int i = 0; i < 2; ++i) {
            float4 av = *(const float4*)(xg + (size_t)(i * 64) * KDIM + k0);
            const int r = lrow + i * 64;
            As[lcol + 0][r] = (double)av.x;
            As[lcol + 1][r] = (double)av.y;
            As[lcol + 2][r] = (double)av.z;
            As[lcol + 3][r] = (double)av.w;
        }
        // stage B: 128 rows x 16 k, masked
#pragma unroll
        for (int i = 0; i < 2; ++i) {
            float4 wv = *(const float4*)(wg + (size_t)(i * 64) * KDIM + k0);
            int4   mv = *(const int4*)(mg + (size_t)(i * 64) * KDIM + k0);
            const int r = lrow + i * 64;
            Bs[lcol + 0][r] = mv.x ? (double)wv.x : 0.0;
            Bs[lcol + 1][r] = mv.y ? (double)wv.y : 0.0;
            Bs[lcol + 2][r] = mv.z ? (double)wv.z : 0.0;
            Bs[lcol + 3][r] = mv.w ? (double)wv.w : 0.0;
        }
        __syncthreads();
#pragma unroll
        for (int kk = 0; kk < BK; ++kk) {
            double a[8], b[8];
#pragma unroll
            for (int i = 0; i < 8; ++i) a[i] = As[kk][ty * 8 + i];
#pragma unroll
            for (int j = 0; j < 4; ++j) {
                b[2 * j + 0] = Bs[kk][2 * tx + 32 * j + 0];
                b[2 * j + 1] = Bs[kk][2 * tx + 32 * j + 1];
            }
#pragma unroll
            for (int i = 0; i < 8; ++i)
#pragma unroll
                for (int j = 0; j < 8; ++j)
                    acc[i][j] = fma(a[i], b[j], acc[i][j]);
        }
        __syncthreads();
    }

    // epilogue: + bias, split hi/lo, store float2 per column-pair
    double bb[8];
#pragma unroll
    for (int j = 0; j < 4; ++j) {
        bb[2 * j + 0] = (double)bias[n0 + 2 * tx + 32 * j + 0];
        bb[2 * j + 1] = (double)bias[n0 + 2 * tx + 32 * j + 1];
    }
#pragma unroll
    for (int r = 0; r < 8; ++r) {
        const size_t rowoff = (size_t)(m0 + ty * 8 + r) * NDEN + n0 + 2 * tx;
#pragma unroll
        for (int j = 0; j < 4; ++j) {
            double v0 = acc[r][2 * j + 0] + bb[2 * j + 0];
            double v1 = acc[r][2 * j + 1] + bb[2 * j + 1];
            float h0 = (float)v0, h1 = (float)v1;
            float l0 = (float)(v0 - (double)h0), l1 = (float)(v1 - (double)h1);
            float2 oh = { h0, h1 };
            float2 ol = { l0, l1 };
            *(float2*)(yhi + rowoff + 32 * j) = oh;
            *(float2*)(ylo + rowoff + 32 * j) = ol;
        }
    }
}

// ---------------- kernel 2: exact f64-key top-k (no band machinery) ----------------
__device__ __forceinline__ u64 dkey(double f) {
    u64 u = (u64)__double_as_longlong(f);
    return (u & 0x8000000000000000ull) ? ~u : (u | 0x8000000000000000ull);
}

__global__ __launch_bounds__(256) void topk64(
    float* __restrict__ yhi, const float* __restrict__ ylo,
    const double* __restrict__ boost)
{
    const int row  = blockIdx.x;
    const int tid  = threadIdx.x;
    const int lane = tid & 63;
    float* hrow = yhi + (size_t)row * NDEN;
    const float* lrow = ylo + (size_t)row * NDEN;

    __shared__ unsigned cnt[64];
    if (tid < 64) cnt[tid] = 0u;

    // exact f64 score keys, 32 per thread
    u64 kv[32];
#pragma unroll
    for (int i = 0; i < 8; ++i) {
        float4 h = ((const float4*)hrow)[i * 256 + tid];
        float4 l = ((const float4*)lrow)[i * 256 + tid];
        const int col0 = (i * 256 + tid) * 4;
        kv[i * 4 + 0] = dkey(((double)h.x + (double)l.x) * boost[col0 + 0]);
        kv[i * 4 + 1] = dkey(((double)h.y + (double)l.y) * boost[col0 + 1]);
        kv[i * 4 + 2] = dkey(((double)h.z + (double)l.z) * boost[col0 + 2]);
        kv[i * 4 + 3] = dkey(((double)h.w + (double)l.w) * boost[col0 + 3]);
    }
    __syncthreads();

    // 64-bit radix bisect for the K-th largest key
    u64 prefix = 0ull;
    for (int b = 63; b >= 0; --b) {
        const u64 t = prefix | (1ull << b);
        int c = 0;
#pragma unroll
        for (int j = 0; j < 32; ++j) c += (kv[j] >= t) ? 1 : 0;
#pragma unroll
        for (int off = 32; off > 0; off >>= 1) c += __shfl_down(c, off);
        if (lane == 0) atomicAdd(&cnt[b], (unsigned)c);
        __syncthreads();
        if (cnt[b] >= TOPK) prefix = t;
    }

    // winners: key >= prefix (prefix == exact K-th largest f64 key)
#pragma unroll
    for (int i = 0; i < 8; ++i) {
        float4 h = ((const float4*)hrow)[i * 256 + tid];
        float4 o;
        o.x = (kv[i * 4 + 0] >= prefix) ? h.x : 0.0f;
        o.y = (kv[i * 4 + 1] >= prefix) ? h.y : 0.0f;
        o.z = (kv[i * 4 + 2] >= prefix) ? h.z : 0.0f;
        o.w = (kv[i * 4 + 3] >= prefix) ? h.w : 0.0f;
        ((float4*)hrow)[i * 256 + tid] = o;
    }
}

// ---------------- launcher ----------------
extern "C" void kernel_launch(void* const* d_in, const int* in_sizes, int n_in,
                              void* d_out, int out_size, void* d_ws, size_t ws_size,
                              hipStream_t stream) {
    const float* x     = (const float*)d_in[0];
    const float* w     = (const float*)d_in[1];
    const float* bias  = (const float*)d_in[2];
    const float* duty  = (const float*)d_in[3];
    const int*   wmask = (const int*)d_in[4];

    float*  yhi   = (float*)d_out;
    float*  ylo   = (float*)d_ws;                                      // 268435456 B
    double* boost = (double*)((char*)d_ws + (size_t)BATCH * NDEN * 4); // +65536 B

    boost64_kernel<<<NDEN / 256, 256, 0, stream>>>(duty, boost);
    dim3 grid(NDEN / 128, BATCH / 128);
    masked_gemm_f64<<<grid, 256, 0, stream>>>(x, w, wmask, bias, yhi, ylo);
    topk64<<<BATCH, 256, 0, stream>>>(yhi, ylo, boost);
}